// Round 15
// baseline (76.279 us; speedup 1.0000x reference)
//
#include <hip/hip_runtime.h>
#include <hip/hip_bf16.h>
#include <math.h>

// AttentionBlock3D: b=1, C=256, n=4096, 8 heads x 32 dim, GROUPS=8, EPS=1e-5
// r15 pipeline (4 dispatches) = r14 fusion + r12's verified attn_step:
//  KA xt_gn:    x f32 [256][4096] -> xTb bf16 [4096][256] + gn partial sums
//  KC gemm_qkv: stats+fold INLINE (per-block psum2 reduce, w_qkv folded to
//               bf16 on the fly, bias row-dots by 64 thr -> LDS), then bf16
//               MFMA GEMM -> qt[h][pos][32] (Q pre-scaled LOG2E/sqrt(d)),
//               ktb[h][pos][32], v16[h][j/16][32][16]
//  KD attn:     r12 attn_step restored (per-it QK->exp->PV; r14's phase
//               clustering REVERTED - it regressed 68.6->75.1, likely VGPR
//               pressure from st[2][4]+pb[2][4] live across clusters).
//               No online max, truncation pack, ones-MFMA denominator,
//               2x-unrolled jt prefetch, chunked merge.
//  KE gemm_out: w_out cast inline (f32 loads -> bf16 frags), bf16 MFMA,
//               y = w_out @ outTb^T + b_out (f32 out)

typedef __attribute__((ext_vector_type(8))) short bf16x8;
typedef __attribute__((ext_vector_type(4))) short bf16x4;
typedef __attribute__((ext_vector_type(4))) float f32x4;
typedef __attribute__((ext_vector_type(4))) unsigned short u16x4;

__device__ inline unsigned short f2bf(float f) {
  __hip_bfloat16 h = __float2bfloat16(f);
  return *reinterpret_cast<unsigned short*>(&h);
}

// ---------------- KA: transpose + groupnorm partial sums ----------------
__global__ __launch_bounds__(256) void xt_gn_kernel(const float* __restrict__ x,
                                                    unsigned short* __restrict__ xTb,
                                                    float2* __restrict__ psum2) {
  __shared__ float tile[64][65];
  __shared__ float red[4][4];
  int nb = blockIdx.x * 64, cb = blockIdx.y * 64;
  int tn = threadIdx.x & 63, t4 = threadIdx.x >> 6;
  float slo = 0.f, qlo = 0.f, shi = 0.f, qhi = 0.f;
#pragma unroll
  for (int i = 0; i < 16; ++i) {
    int cc = t4 + i * 4;
    float v = x[(size_t)(cb + cc) * 4096 + nb + tn];
    tile[cc][tn] = v;
    if (i < 8) { slo += v; qlo += v * v; } else { shi += v; qhi += v * v; }
  }
#pragma unroll
  for (int off = 32; off > 0; off >>= 1) {
    slo += __shfl_down(slo, off); qlo += __shfl_down(qlo, off);
    shi += __shfl_down(shi, off); qhi += __shfl_down(qhi, off);
  }
  if ((threadIdx.x & 63) == 0) {
    red[t4][0] = slo; red[t4][1] = qlo; red[t4][2] = shi; red[t4][3] = qhi;
  }
  __syncthreads();
  if (threadIdx.x == 0) {
    float a = (red[0][0] + red[1][0]) + (red[2][0] + red[3][0]);
    float b = (red[0][1] + red[1][1]) + (red[2][1] + red[3][1]);
    psum2[(blockIdx.y * 2) * 64 + blockIdx.x] = make_float2(a, b);
  } else if (threadIdx.x == 64) {
    float a = (red[0][2] + red[1][2]) + (red[2][2] + red[3][2]);
    float b = (red[0][3] + red[1][3]) + (red[2][3] + red[3][3]);
    psum2[(blockIdx.y * 2 + 1) * 64 + blockIdx.x] = make_float2(a, b);
  }
#pragma unroll
  for (int i = 0; i < 16; ++i) {
    int nn = t4 + i * 4;
    xTb[(size_t)(nb + nn) * 256 + cb + tn] = f2bf(tile[tn][nn]);
  }
}

// ---------------- KC: qkv GEMM with inline groupnorm fold ----------------
__global__ __launch_bounds__(256) void gemm_qkv_mfma(const float* __restrict__ w_qkv,
                                                     const unsigned short* __restrict__ xTb,
                                                     const float* __restrict__ gnw,
                                                     const float* __restrict__ gnb,
                                                     const float2* __restrict__ psum2,
                                                     unsigned short* __restrict__ qt,
                                                     unsigned short* __restrict__ ktb,
                                                     unsigned short* __restrict__ v16) {
  const int nb = blockIdx.x, mb = blockIdx.y;
  const int t = threadIdx.x;
  const int w = t >> 6, lane = t & 63;
  const int c = lane & 15, g = lane >> 4;
  const int m0 = mb * 64 + w * 16;
  const int n0 = nb * 64;
  const f32x4 zero4 = {0.f, 0.f, 0.f, 0.f};

  __shared__ float sm[8], sr[8];
  __shared__ float s_al[256], s_be[256];
  __shared__ float bias_s[64];
  {  // per-block redundant stats reduce (4KB psum2)
    int gg = t >> 5, ii = t & 31;
    float2 p0 = psum2[gg * 64 + ii];
    float2 p1 = psum2[gg * 64 + 32 + ii];
    float s = p0.x + p1.x, q = p0.y + p1.y;
#pragma unroll
    for (int off = 16; off > 0; off >>= 1) {
      s += __shfl_xor(s, off);
      q += __shfl_xor(q, off);
    }
    if (ii == 0) {
      float mean = s * (1.f / 131072.f);
      float var = q * (1.f / 131072.f) - mean * mean;
      sm[gg] = mean;
      sr[gg] = rsqrtf(var + 1e-5f);
    }
  }
  __syncthreads();
  {
    int cc = t, gg = cc >> 5;
    float mean = sm[gg], rstd = sr[gg];
    float al = rstd * gnw[cc];
    s_al[cc] = al;
    s_be[cc] = gnb[cc] - mean * al;
  }
  __syncthreads();
  // bias for this block's 64 output rows (one thread per row)
  if (t < 64) {
    int row = mb * 64 + t;
    const float* wr = w_qkv + (size_t)row * 256;
    float sum = 0.f;
#pragma unroll 8
    for (int k = 0; k < 256; k += 4) {
      float4 v = *(const float4*)(wr + k);
      sum += (v.x * s_be[k] + v.y * s_be[k + 1]) + (v.z * s_be[k + 2] + v.w * s_be[k + 3]);
    }
    bias_s[t] = sum;
  }
  // A fragments: fold w_qkv * alpha on the fly -> bf16
  const float* ap = w_qkv + (size_t)(m0 + c) * 256 + g * 8;
  bf16x8 af[8];
#pragma unroll
  for (int ks = 0; ks < 8; ++ks) {
    float4 a0 = *(const float4*)(ap + ks * 32);
    float4 a1 = *(const float4*)(ap + ks * 32 + 4);
    int e0 = ks * 32 + g * 8;
    bf16x8 v;
    v[0] = (short)f2bf(a0.x * s_al[e0 + 0]);
    v[1] = (short)f2bf(a0.y * s_al[e0 + 1]);
    v[2] = (short)f2bf(a0.z * s_al[e0 + 2]);
    v[3] = (short)f2bf(a0.w * s_al[e0 + 3]);
    v[4] = (short)f2bf(a1.x * s_al[e0 + 4]);
    v[5] = (short)f2bf(a1.y * s_al[e0 + 5]);
    v[6] = (short)f2bf(a1.z * s_al[e0 + 6]);
    v[7] = (short)f2bf(a1.w * s_al[e0 + 7]);
    af[ks] = v;
  }
  __syncthreads();  // bias_s ready for epilogue

  f32x4 acc[4] = {zero4, zero4, zero4, zero4};
  const unsigned short* bp = xTb + (size_t)(n0 + c) * 256 + g * 8;
#pragma unroll
  for (int half = 0; half < 2; ++half) {
    bf16x8 bf[4][4];
#pragma unroll
    for (int nt = 0; nt < 4; ++nt)
#pragma unroll
      for (int k2 = 0; k2 < 4; ++k2)
        bf[nt][k2] = *(const bf16x8*)(bp + (size_t)nt * 4096 + half * 128 + k2 * 32);
#pragma unroll
    for (int k2 = 0; k2 < 4; ++k2)
#pragma unroll
      for (int nt = 0; nt < 4; ++nt)
        acc[nt] = __builtin_amdgcn_mfma_f32_16x16x32_bf16(af[half * 4 + k2], bf[nt][k2],
                                                          acc[nt], 0, 0, 0);
  }

  const int o0 = m0 + g * 4;
  const int t3 = o0 >> 8;
  const int h = (o0 >> 5) & 7;
  const int d0 = o0 & 31;
  float b4[4];
#pragma unroll
  for (int r = 0; r < 4; ++r) b4[r] = bias_s[w * 16 + g * 4 + r];
  // Q pre-scale: 1/sqrt(32) * log2(e) so scores exit QK^T in log2 units
  const float qs = 0.17677669529663687f * 1.4426950408889634f;
#pragma unroll
  for (int nt = 0; nt < 4; ++nt) {
    int n = n0 + nt * 16 + c;
    if (t3 == 0) {
      u16x4 v;
#pragma unroll
      for (int r = 0; r < 4; ++r) v[r] = f2bf((acc[nt][r] + b4[r]) * qs);
      *(u16x4*)(qt + (size_t)(h * 4096 + n) * 32 + d0) = v;
    } else if (t3 == 1) {
      u16x4 v;
#pragma unroll
      for (int r = 0; r < 4; ++r) v[r] = f2bf(acc[nt][r] + b4[r]);
      *(u16x4*)(ktb + (size_t)(h * 4096 + n) * 32 + d0) = v;
    } else {
#pragma unroll
      for (int r = 0; r < 4; ++r)
        v16[(size_t)((h * 256 + (n >> 4)) * 32 + d0 + r) * 16 + (n & 15)] =
            f2bf(acc[nt][r] + b4[r]);
    }
  }
}

// ---------------- KD: MFMA flash attention, no online max ----------------
// r12 attn_step (verified best): per-it QK MFMAs -> exp2+trunc pack ->
// PV/lones MFMAs. Truncation pack; ones-MFMA denominator over the SAME
// truncated bits (self-consistent -> bias cancels in p/l; fp32 accum).
__device__ __forceinline__ void attn_step(const bf16x8* kf, const bf16x4 vf[2][4],
                                          const bf16x8* qf, f32x4 (*oacc)[2],
                                          f32x4* lones) {
  const f32x4 zero4 = {0.f, 0.f, 0.f, 0.f};
  const short one_bf = (short)0x3F80;
  const bf16x4 onesv = {one_bf, one_bf, one_bf, one_bf};
#pragma unroll
  for (int it = 0; it < 4; ++it) {
    f32x4 st[4];
    __builtin_amdgcn_s_setprio(1);
#pragma unroll
    for (int js = 0; js < 4; ++js)
      st[js] = __builtin_amdgcn_mfma_f32_16x16x32_bf16(kf[js], qf[it], zero4, 0, 0, 0);
    __builtin_amdgcn_s_setprio(0);
    bf16x4 pb[4];
#pragma unroll
    for (int js = 0; js < 4; ++js) {
      // scores already in log2 units (Q pre-scaled by LOG2E/sqrt(d))
      unsigned u0 = __float_as_uint(__builtin_amdgcn_exp2f(st[js][0]));
      unsigned u1 = __float_as_uint(__builtin_amdgcn_exp2f(st[js][1]));
      unsigned u2 = __float_as_uint(__builtin_amdgcn_exp2f(st[js][2]));
      unsigned u3 = __float_as_uint(__builtin_amdgcn_exp2f(st[js][3]));
      union { unsigned u[2]; bf16x4 v; } pu;
      pu.u[0] = (u0 >> 16) | (u1 & 0xFFFF0000u);  // elem0=bf16(p0), elem1=bf16(p1)
      pu.u[1] = (u2 >> 16) | (u3 & 0xFFFF0000u);
      pb[js] = pu.v;
    }
    __builtin_amdgcn_s_setprio(1);
#pragma unroll
    for (int js = 0; js < 4; ++js) {
      oacc[it][0] = __builtin_amdgcn_mfma_f32_16x16x16bf16_1k(vf[0][js], pb[js], oacc[it][0], 0, 0, 0);
      oacc[it][1] = __builtin_amdgcn_mfma_f32_16x16x16bf16_1k(vf[1][js], pb[js], oacc[it][1], 0, 0, 0);
      lones[it] = __builtin_amdgcn_mfma_f32_16x16x16bf16_1k(onesv, pb[js], lones[it], 0, 0, 0);
    }
    __builtin_amdgcn_s_setprio(0);
  }
}

// 512 blocks x 512 threads. h = b>>6, i0 = (b&63)*64. 8 waves split j
// (512 each). 2x-unrolled jt pipeline, two K+V register sets.
__global__ __launch_bounds__(512, 1) void attn_mfma_kernel(const unsigned short* __restrict__ qt,
                                                           const unsigned short* __restrict__ ktb,
                                                           const unsigned short* __restrict__ v16,
                                                           unsigned short* __restrict__ outTb) {
  const int b = blockIdx.x;
  const int h = b >> 6;
  const int i0 = (b & 63) * 64;
  const int t = threadIdx.x;
  const int w = t >> 6;
  const int lane = t & 63;
  const int c = lane & 15;
  const int g = lane >> 4;
  const f32x4 zero4 = {0.f, 0.f, 0.f, 0.f};

  const unsigned short* qb = qt + (size_t)h * 131072 + (size_t)(i0 + c) * 32 + g * 8;
  bf16x8 qf[4];
#pragma unroll
  for (int it = 0; it < 4; ++it) qf[it] = *(const bf16x8*)(qb + it * 512);

  const unsigned short* kp = ktb + (size_t)h * 131072 + (size_t)(w * 512 + c) * 32 + g * 8;
  const unsigned short* vp = v16 + (size_t)((h * 256 + w * 32) * 32 + c) * 16 + g * 4;

  f32x4 lones[4] = {zero4, zero4, zero4, zero4};
  f32x4 oacc[4][2];
#pragma unroll
  for (int it = 0; it < 4; ++it) {
    oacc[it][0] = zero4;
    oacc[it][1] = zero4;
  }

#define KLOAD(dst, tt)                                         \
  _Pragma("unroll") for (int js = 0; js < 4; ++js)             \
      dst[js] = *(const bf16x8*)(kp + (tt) * 2048 + js * 512);
#define VLOAD(dst, tt)                                                        \
  _Pragma("unroll") for (int dh = 0; dh < 2; ++dh)                            \
      _Pragma("unroll") for (int js = 0; js < 4; ++js)                        \
          dst[dh][js] = *(const bf16x4*)(vp + ((tt) * 4 + js) * 512 + dh * 256);

  bf16x8 kfA[4], kfB[4];
  bf16x4 vfA[2][4], vfB[2][4];
  KLOAD(kfA, 0);
  VLOAD(vfA, 0);

#pragma unroll 1
  for (int jt2 = 0; jt2 < 4; ++jt2) {
    const int base = jt2 * 2;
    KLOAD(kfB, base + 1);
    VLOAD(vfB, base + 1);
    attn_step(kfA, vfA, qf, oacc, lones);
    if (jt2 < 3) {
      KLOAD(kfA, base + 2);
      VLOAD(vfA, base + 2);
    }
    attn_step(kfB, vfB, qf, oacc, lones);
  }
#undef KLOAD
#undef VLOAD

  // ---- merge 8 waves' partials, chunked per i-tile (LDS ~19.5KB) ----
  // ones-MFMA puts the full column sum in every acc element, so
  // lones[it][0] is the per-query denominator directly (no shfl needed).
  __shared__ float lds_o[8][2][4][4][17];  // [w][dh][g][r][c] (one i-tile)
  __shared__ float lds_l[8][4][16];
#pragma unroll
  for (int it = 0; it < 4; ++it) {
    if (g == 0) lds_l[w][it][c] = lones[it][0];
  }
#pragma unroll 1
  for (int itc = 0; itc < 4; ++itc) {
#pragma unroll
    for (int dh = 0; dh < 2; ++dh)
#pragma unroll
      for (int r = 0; r < 4; ++r)
        lds_o[w][dh][g][r][c] = oacc[itc][dh][r];
    __syncthreads();
    if (w < 2) {
      const int dh = w;
      float L = ((lds_l[0][itc][c] + lds_l[1][itc][c]) + (lds_l[2][itc][c] + lds_l[3][itc][c])) +
                ((lds_l[4][itc][c] + lds_l[5][itc][c]) + (lds_l[6][itc][c] + lds_l[7][itc][c]));
      float inv = 1.f / L;
      u16x4 o;
#pragma unroll
      for (int r = 0; r < 4; ++r) {
        float v = ((lds_o[0][dh][g][r][c] + lds_o[1][dh][g][r][c]) +
                   (lds_o[2][dh][g][r][c] + lds_o[3][dh][g][r][c])) +
                  ((lds_o[4][dh][g][r][c] + lds_o[5][dh][g][r][c]) +
                   (lds_o[6][dh][g][r][c] + lds_o[7][dh][g][r][c]));
        o[r] = f2bf(v * inv);
      }
      *(u16x4*)(outTb + (size_t)(i0 + itc * 16 + c) * 256 + h * 32 + dh * 16 + g * 4) = o;
    }
    __syncthreads();
  }
}

// ---------------- KE: y = w_out @ outTb^T + b_out (inline cast) ----------------
__global__ __launch_bounds__(256) void gemm_out_mfma(const float* __restrict__ w_out,
                                                     const unsigned short* __restrict__ outTb,
                                                     const float* __restrict__ bias,
                                                     float* __restrict__ y) {
  const int nb = blockIdx.x, mb = blockIdx.y;
  const int t = threadIdx.x;
  const int w = t >> 6, lane = t & 63;
  const int c = lane & 15, g = lane >> 4;
  const int m0 = mb * 64 + w * 16;
  const int n0 = nb * 64;
  const f32x4 zero4 = {0.f, 0.f, 0.f, 0.f};

  const float* ap = w_out + (size_t)(m0 + c) * 256 + g * 8;
  bf16x8 af[8];
#pragma unroll
  for (int ks = 0; ks < 8; ++ks) {
    float4 a0 = *(const float4*)(ap + ks * 32);
    float4 a1 = *(const float4*)(ap + ks * 32 + 4);
    bf16x8 v;
    v[0] = (short)f2bf(a0.x); v[1] = (short)f2bf(a0.y);
    v[2] = (short)f2bf(a0.z); v[3] = (short)f2bf(a0.w);
    v[4] = (short)f2bf(a1.x); v[5] = (short)f2bf(a1.y);
    v[6] = (short)f2bf(a1.z); v[7] = (short)f2bf(a1.w);
    af[ks] = v;
  }

  f32x4 acc[4] = {zero4, zero4, zero4, zero4};
  const unsigned short* bp = outTb + (size_t)(n0 + c) * 256 + g * 8;
#pragma unroll
  for (int half = 0; half < 2; ++half) {
    bf16x8 bf[4][4];
#pragma unroll
    for (int nt = 0; nt < 4; ++nt)
#pragma unroll
      for (int k2 = 0; k2 < 4; ++k2)
        bf[nt][k2] = *(const bf16x8*)(bp + (size_t)nt * 4096 + half * 128 + k2 * 32);
#pragma unroll
    for (int k2 = 0; k2 < 4; ++k2)
#pragma unroll
      for (int nt = 0; nt < 4; ++nt)
        acc[nt] = __builtin_amdgcn_mfma_f32_16x16x32_bf16(af[half * 4 + k2], bf[nt][k2],
                                                          acc[nt], 0, 0, 0);
  }

  const int o0 = m0 + g * 4;
  float b4[4];
#pragma unroll
  for (int r = 0; r < 4; ++r) b4[r] = bias[o0 + r];
#pragma unroll
  for (int nt = 0; nt < 4; ++nt) {
    int n = n0 + nt * 16 + c;
#pragma unroll
    for (int r = 0; r < 4; ++r)
      y[(size_t)(o0 + r) * 4096 + n] = acc[nt][r] + b4[r];
  }
}

extern "C" void kernel_launch(void* const* d_in, const int* in_sizes, int n_in,
                              void* d_out, int out_size, void* d_ws, size_t ws_size,
                              hipStream_t stream) {
  const float* x = (const float*)d_in[0];
  const float* gnw = (const float*)d_in[1];
  const float* gnb = (const float*)d_in[2];
  const float* w_qkv = (const float*)d_in[3];
  const float* w_out = (const float*)d_in[4];
  const float* b_out = (const float*)d_in[5];
  float* ws = (float*)d_ws;

  float2* psum2 = (float2*)ws;                         // 512 float2
  unsigned short* xTb = (unsigned short*)(ws + 2048);  // 4096*256 u16
  unsigned short* qt = xTb + 1048576;                  // 8*4096*32 u16
  unsigned short* ktb = qt + 1048576;
  unsigned short* v16 = ktb + 1048576;                 // tiled V
  unsigned short* outTb = v16 + 1048576;               // 4096*256 u16
  float* y = (float*)d_out;

  hipLaunchKernelGGL(xt_gn_kernel, dim3(64, 4), dim3(256), 0, stream, x, xTb, psum2);
  hipLaunchKernelGGL(gemm_qkv_mfma, dim3(64, 12), dim3(256), 0, stream, w_qkv, xTb,
                     gnw, gnb, psum2, qt, ktb, v16);
  hipLaunchKernelGGL(attn_mfma_kernel, dim3(512), dim3(512), 0, stream, qt, ktb, v16, outTb);
  hipLaunchKernelGGL(gemm_out_mfma, dim3(64, 4), dim3(256), 0, stream, w_out, outTb, b_out, y);
}

// Round 16
// 72.977 us; speedup vs baseline: 1.0453x; 1.0453x over previous
//
#include <hip/hip_runtime.h>
#include <hip/hip_bf16.h>
#include <math.h>

// AttentionBlock3D: b=1, C=256, n=4096, 8 heads x 32 dim, GROUPS=8, EPS=1e-5
// r16 = r12 pipeline (5 dispatches; KB un-fused — r14/r15 proved fusion
// costs ~7us from per-block refold) + attn at 128 q/block (halves K/V
// cache-fabric traffic 268MB -> 134MB; r7 vs r8 slope says attn is
// substantially L2/L3-BW-bound).
//  KA xt_gn:    x f32 [256][4096] -> xTb bf16 [4096][256] + gn partial sums
//  KB fold_all: stats + fold groupnorm into QKV weights (w2b bf16, bias0)
//               + w_out cast (ONCE, 256 blocks)
//  KC gemm_qkv: bf16 MFMA -> qt[h][pos][32] (Q pre-scaled LOG2E/sqrt(d)),
//               ktb[h][pos][32], v16[h][j/16][32][16]
//  KD attn:     r12 attn_step (per-it QK->exp->PV, truncation pack,
//               ones-MFMA denominator). 256 blocks x 512 thr, 128 q/block
//               (8 i-tiles), 8 waves j-split (512 each), 2x-unrolled
//               K/V prefetch, chunked per-i-tile merge.
//  KE gemm_out: y = w_outb @ outTb^T + b_out (bf16 MFMA, f32 out)

typedef __attribute__((ext_vector_type(8))) short bf16x8;
typedef __attribute__((ext_vector_type(4))) short bf16x4;
typedef __attribute__((ext_vector_type(4))) float f32x4;
typedef __attribute__((ext_vector_type(4))) unsigned short u16x4;

__device__ inline unsigned short f2bf(float f) {
  __hip_bfloat16 h = __float2bfloat16(f);
  return *reinterpret_cast<unsigned short*>(&h);
}

// ---------------- KA: transpose + groupnorm partial sums ----------------
__global__ __launch_bounds__(256) void xt_gn_kernel(const float* __restrict__ x,
                                                    unsigned short* __restrict__ xTb,
                                                    float2* __restrict__ psum2) {
  __shared__ float tile[64][65];
  __shared__ float red[4][4];
  int nb = blockIdx.x * 64, cb = blockIdx.y * 64;
  int tn = threadIdx.x & 63, t4 = threadIdx.x >> 6;
  float slo = 0.f, qlo = 0.f, shi = 0.f, qhi = 0.f;
#pragma unroll
  for (int i = 0; i < 16; ++i) {
    int cc = t4 + i * 4;
    float v = x[(size_t)(cb + cc) * 4096 + nb + tn];
    tile[cc][tn] = v;
    if (i < 8) { slo += v; qlo += v * v; } else { shi += v; qhi += v * v; }
  }
#pragma unroll
  for (int off = 32; off > 0; off >>= 1) {
    slo += __shfl_down(slo, off); qlo += __shfl_down(qlo, off);
    shi += __shfl_down(shi, off); qhi += __shfl_down(qhi, off);
  }
  if ((threadIdx.x & 63) == 0) {
    red[t4][0] = slo; red[t4][1] = qlo; red[t4][2] = shi; red[t4][3] = qhi;
  }
  __syncthreads();
  if (threadIdx.x == 0) {
    float a = (red[0][0] + red[1][0]) + (red[2][0] + red[3][0]);
    float b = (red[0][1] + red[1][1]) + (red[2][1] + red[3][1]);
    psum2[(blockIdx.y * 2) * 64 + blockIdx.x] = make_float2(a, b);
  } else if (threadIdx.x == 64) {
    float a = (red[0][2] + red[1][2]) + (red[2][2] + red[3][2]);
    float b = (red[0][3] + red[1][3]) + (red[2][3] + red[3][3]);
    psum2[(blockIdx.y * 2 + 1) * 64 + blockIdx.x] = make_float2(a, b);
  }
#pragma unroll
  for (int i = 0; i < 16; ++i) {
    int nn = t4 + i * 4;
    xTb[(size_t)(nb + nn) * 256 + cb + tn] = f2bf(tile[tn][nn]);
  }
}

// ---------------- KB: stats + fold + w_out cast ----------------
__global__ __launch_bounds__(256) void fold_all_kernel(const float* __restrict__ w_qkv,
                                                       const float* __restrict__ gnw,
                                                       const float* __restrict__ gnb,
                                                       const float2* __restrict__ psum2,
                                                       const float* __restrict__ w_out,
                                                       unsigned short* __restrict__ w2b,
                                                       float* __restrict__ bias0,
                                                       unsigned short* __restrict__ w_outb) {
  int bid = blockIdx.x;
  int t = threadIdx.x;
  if (bid >= 192) {  // w_out -> bf16
    int i = ((bid - 192) * 256 + t) * 4;
    float4 v = *(const float4*)(w_out + i);
    u16x4 o;
    o[0] = f2bf(v.x); o[1] = f2bf(v.y); o[2] = f2bf(v.z); o[3] = f2bf(v.w);
    *(u16x4*)(w_outb + i) = o;
    return;
  }
  __shared__ float sm[8], sr[8];
  __shared__ float s_al[256], s_be[256];
  {
    int g = t >> 5, ii = t & 31;
    float2 p0 = psum2[g * 64 + ii];
    float2 p1 = psum2[g * 64 + 32 + ii];
    float s = p0.x + p1.x, q = p0.y + p1.y;
#pragma unroll
    for (int off = 16; off > 0; off >>= 1) {
      s += __shfl_xor(s, off);
      q += __shfl_xor(q, off);
    }
    if (ii == 0) {
      float mean = s * (1.f / 131072.f);
      float var = q * (1.f / 131072.f) - mean * mean;
      sm[g] = mean;
      sr[g] = rsqrtf(var + 1e-5f);
    }
  }
  __syncthreads();
  {
    int c = t, gg = c >> 5;
    float mean = sm[gg], rstd = sr[gg];
    float al = rstd * gnw[c];
    s_al[c] = al;
    s_be[c] = gnb[c] - mean * al;
  }
  __syncthreads();
  int w = t >> 6, lane = t & 63;
  int row = bid * 4 + w;
  float4 v = *(const float4*)(w_qkv + row * 256 + lane * 4);
  int c0 = lane * 4;
  float part = (v.x * s_be[c0] + v.y * s_be[c0 + 1]) +
               (v.z * s_be[c0 + 2] + v.w * s_be[c0 + 3]);
  u16x4 o;
  o[0] = f2bf(v.x * s_al[c0]);
  o[1] = f2bf(v.y * s_al[c0 + 1]);
  o[2] = f2bf(v.z * s_al[c0 + 2]);
  o[3] = f2bf(v.w * s_al[c0 + 3]);
  *(u16x4*)(w2b + row * 256 + c0) = o;
#pragma unroll
  for (int off = 32; off > 0; off >>= 1) part += __shfl_down(part, off);
  if (lane == 0) bias0[row] = part;
}

// ---------------- KC: qkv GEMM, bf16 MFMA ----------------
__global__ __launch_bounds__(256) void gemm_qkv_mfma(const unsigned short* __restrict__ w2b,
                                                     const unsigned short* __restrict__ xTb,
                                                     const float* __restrict__ bias0,
                                                     unsigned short* __restrict__ qt,
                                                     unsigned short* __restrict__ ktb,
                                                     unsigned short* __restrict__ v16) {
  const int nb = blockIdx.x, mb = blockIdx.y;
  const int t = threadIdx.x;
  const int w = t >> 6, lane = t & 63;
  const int c = lane & 15, g = lane >> 4;
  const int m0 = mb * 64 + w * 16;
  const int n0 = nb * 64;
  const f32x4 zero4 = {0.f, 0.f, 0.f, 0.f};

  const unsigned short* ap = w2b + (size_t)(m0 + c) * 256 + g * 8;
  bf16x8 af[8];
#pragma unroll
  for (int ks = 0; ks < 8; ++ks) af[ks] = *(const bf16x8*)(ap + ks * 32);

  f32x4 acc[4] = {zero4, zero4, zero4, zero4};
  const unsigned short* bp = xTb + (size_t)(n0 + c) * 256 + g * 8;
#pragma unroll
  for (int half = 0; half < 2; ++half) {
    bf16x8 bf[4][4];
#pragma unroll
    for (int nt = 0; nt < 4; ++nt)
#pragma unroll
      for (int k2 = 0; k2 < 4; ++k2)
        bf[nt][k2] = *(const bf16x8*)(bp + (size_t)nt * 4096 + half * 128 + k2 * 32);
#pragma unroll
    for (int k2 = 0; k2 < 4; ++k2)
#pragma unroll
      for (int nt = 0; nt < 4; ++nt)
        acc[nt] = __builtin_amdgcn_mfma_f32_16x16x32_bf16(af[half * 4 + k2], bf[nt][k2],
                                                          acc[nt], 0, 0, 0);
  }

  const int o0 = m0 + g * 4;
  const int t3 = o0 >> 8;
  const int h = (o0 >> 5) & 7;
  const int d0 = o0 & 31;
  float b4[4];
#pragma unroll
  for (int r = 0; r < 4; ++r) b4[r] = bias0[o0 + r];
  // Q pre-scale: 1/sqrt(32) * log2(e) so scores exit QK^T in log2 units
  const float qs = 0.17677669529663687f * 1.4426950408889634f;
#pragma unroll
  for (int nt = 0; nt < 4; ++nt) {
    int n = n0 + nt * 16 + c;
    if (t3 == 0) {
      u16x4 v;
#pragma unroll
      for (int r = 0; r < 4; ++r) v[r] = f2bf((acc[nt][r] + b4[r]) * qs);
      *(u16x4*)(qt + (size_t)(h * 4096 + n) * 32 + d0) = v;
    } else if (t3 == 1) {
      u16x4 v;
#pragma unroll
      for (int r = 0; r < 4; ++r) v[r] = f2bf(acc[nt][r] + b4[r]);
      *(u16x4*)(ktb + (size_t)(h * 4096 + n) * 32 + d0) = v;
    } else {
#pragma unroll
      for (int r = 0; r < 4; ++r)
        v16[(size_t)((h * 256 + (n >> 4)) * 32 + d0 + r) * 16 + (n & 15)] =
            f2bf(acc[nt][r] + b4[r]);
    }
  }
}

// ---------------- KD: MFMA flash attention, no online max ----------------
// r12 attn_step generalized to NIT i-tiles: per-it QK MFMAs -> exp2+trunc
// pack -> PV/lones MFMAs. Ones-MFMA denominator over the SAME truncated
// bits (self-consistent; bias cancels in p/l; fp32 accum).
__device__ __forceinline__ void attn_step8(const bf16x8* kf, const bf16x4 vf[2][4],
                                           const bf16x8* qf, f32x4 (*oacc)[2],
                                           f32x4* lones) {
  const f32x4 zero4 = {0.f, 0.f, 0.f, 0.f};
  const short one_bf = (short)0x3F80;
  const bf16x4 onesv = {one_bf, one_bf, one_bf, one_bf};
#pragma unroll
  for (int it = 0; it < 8; ++it) {
    f32x4 st[4];
    __builtin_amdgcn_s_setprio(1);
#pragma unroll
    for (int js = 0; js < 4; ++js)
      st[js] = __builtin_amdgcn_mfma_f32_16x16x32_bf16(kf[js], qf[it], zero4, 0, 0, 0);
    __builtin_amdgcn_s_setprio(0);
    bf16x4 pb[4];
#pragma unroll
    for (int js = 0; js < 4; ++js) {
      // scores already in log2 units (Q pre-scaled by LOG2E/sqrt(d))
      unsigned u0 = __float_as_uint(__builtin_amdgcn_exp2f(st[js][0]));
      unsigned u1 = __float_as_uint(__builtin_amdgcn_exp2f(st[js][1]));
      unsigned u2 = __float_as_uint(__builtin_amdgcn_exp2f(st[js][2]));
      unsigned u3 = __float_as_uint(__builtin_amdgcn_exp2f(st[js][3]));
      union { unsigned u[2]; bf16x4 v; } pu;
      pu.u[0] = (u0 >> 16) | (u1 & 0xFFFF0000u);  // elem0=bf16(p0), elem1=bf16(p1)
      pu.u[1] = (u2 >> 16) | (u3 & 0xFFFF0000u);
      pb[js] = pu.v;
    }
    __builtin_amdgcn_s_setprio(1);
#pragma unroll
    for (int js = 0; js < 4; ++js) {
      oacc[it][0] = __builtin_amdgcn_mfma_f32_16x16x16bf16_1k(vf[0][js], pb[js], oacc[it][0], 0, 0, 0);
      oacc[it][1] = __builtin_amdgcn_mfma_f32_16x16x16bf16_1k(vf[1][js], pb[js], oacc[it][1], 0, 0, 0);
      lones[it] = __builtin_amdgcn_mfma_f32_16x16x16bf16_1k(onesv, pb[js], lones[it], 0, 0, 0);
    }
    __builtin_amdgcn_s_setprio(0);
  }
}

// 256 blocks x 512 threads: h = b&7, i0 = (b>>3)*128 (128 q/block halves
// K/V cache traffic to 134MB). 8 waves split j (512 each), 2x-unrolled jt
// pipeline, two K+V register sets, chunked per-i-tile merge.
__global__ __launch_bounds__(512, 1) void attn_mfma_kernel(const unsigned short* __restrict__ qt,
                                                           const unsigned short* __restrict__ ktb,
                                                           const unsigned short* __restrict__ v16,
                                                           unsigned short* __restrict__ outTb) {
  const int b = blockIdx.x;
  const int h = b & 7;
  const int i0 = (b >> 3) * 128;
  const int t = threadIdx.x;
  const int w = t >> 6;
  const int lane = t & 63;
  const int c = lane & 15;
  const int g = lane >> 4;
  const f32x4 zero4 = {0.f, 0.f, 0.f, 0.f};

  const unsigned short* qb = qt + (size_t)h * 131072 + (size_t)(i0 + c) * 32 + g * 8;
  bf16x8 qf[8];
#pragma unroll
  for (int it = 0; it < 8; ++it) qf[it] = *(const bf16x8*)(qb + it * 512);

  const unsigned short* kp = ktb + (size_t)h * 131072 + (size_t)(w * 512 + c) * 32 + g * 8;
  const unsigned short* vp = v16 + (size_t)((h * 256 + w * 32) * 32 + c) * 16 + g * 4;

  f32x4 lones[8];
  f32x4 oacc[8][2];
#pragma unroll
  for (int it = 0; it < 8; ++it) {
    oacc[it][0] = zero4;
    oacc[it][1] = zero4;
    lones[it] = zero4;
  }

#define KLOAD(dst, tt)                                         \
  _Pragma("unroll") for (int js = 0; js < 4; ++js)             \
      dst[js] = *(const bf16x8*)(kp + (tt) * 2048 + js * 512);
#define VLOAD(dst, tt)                                                        \
  _Pragma("unroll") for (int dh = 0; dh < 2; ++dh)                            \
      _Pragma("unroll") for (int js = 0; js < 4; ++js)                        \
          dst[dh][js] = *(const bf16x4*)(vp + ((tt) * 4 + js) * 512 + dh * 256);

  bf16x8 kfA[4], kfB[4];
  bf16x4 vfA[2][4], vfB[2][4];
  KLOAD(kfA, 0);
  VLOAD(vfA, 0);

#pragma unroll 1
  for (int jt2 = 0; jt2 < 4; ++jt2) {
    const int base = jt2 * 2;
    KLOAD(kfB, base + 1);
    VLOAD(vfB, base + 1);
    attn_step8(kfA, vfA, qf, oacc, lones);
    if (jt2 < 3) {
      KLOAD(kfA, base + 2);
      VLOAD(vfA, base + 2);
    }
    attn_step8(kfB, vfB, qf, oacc, lones);
  }
#undef KLOAD
#undef VLOAD

  // ---- merge 8 waves' partials, chunked per i-tile (LDS ~19.5KB) ----
  // ones-MFMA puts the full column sum in every acc element, so
  // lones[it][0] is the per-query denominator directly (no shfl needed).
  __shared__ float lds_o[8][2][4][4][17];  // [w][dh][g][r][c] (one i-tile)
  __shared__ float lds_l[8][8][16];
#pragma unroll
  for (int it = 0; it < 8; ++it) {
    if (g == 0) lds_l[w][it][c] = lones[it][0];
  }
#pragma unroll 1
  for (int itc = 0; itc < 8; ++itc) {
#pragma unroll
    for (int dh = 0; dh < 2; ++dh)
#pragma unroll
      for (int r = 0; r < 4; ++r)
        lds_o[w][dh][g][r][c] = oacc[itc][dh][r];
    __syncthreads();
    if (w < 2) {
      const int dh = w;
      float L = ((lds_l[0][itc][c] + lds_l[1][itc][c]) + (lds_l[2][itc][c] + lds_l[3][itc][c])) +
                ((lds_l[4][itc][c] + lds_l[5][itc][c]) + (lds_l[6][itc][c] + lds_l[7][itc][c]));
      float inv = 1.f / L;
      u16x4 o;
#pragma unroll
      for (int r = 0; r < 4; ++r) {
        float v = ((lds_o[0][dh][g][r][c] + lds_o[1][dh][g][r][c]) +
                   (lds_o[2][dh][g][r][c] + lds_o[3][dh][g][r][c])) +
                  ((lds_o[4][dh][g][r][c] + lds_o[5][dh][g][r][c]) +
                   (lds_o[6][dh][g][r][c] + lds_o[7][dh][g][r][c]));
        o[r] = f2bf(v * inv);
      }
      *(u16x4*)(outTb + (size_t)(i0 + itc * 16 + c) * 256 + h * 32 + dh * 16 + g * 4) = o;
    }
    __syncthreads();
  }
}

// ---------------- KE: y = w_outb @ outTb^T + b_out (bf16 MFMA) ----------------
__global__ __launch_bounds__(256) void gemm_out_mfma(const unsigned short* __restrict__ w_outb,
                                                     const unsigned short* __restrict__ outTb,
                                                     const float* __restrict__ bias,
                                                     float* __restrict__ y) {
  const int nb = blockIdx.x, mb = blockIdx.y;
  const int t = threadIdx.x;
  const int w = t >> 6, lane = t & 63;
  const int c = lane & 15, g = lane >> 4;
  const int m0 = mb * 64 + w * 16;
  const int n0 = nb * 64;
  const f32x4 zero4 = {0.f, 0.f, 0.f, 0.f};

  const unsigned short* ap = w_outb + (size_t)(m0 + c) * 256 + g * 8;
  bf16x8 af[8];
#pragma unroll
  for (int ks = 0; ks < 8; ++ks) af[ks] = *(const bf16x8*)(ap + ks * 32);

  f32x4 acc[4] = {zero4, zero4, zero4, zero4};
  const unsigned short* bp = outTb + (size_t)(n0 + c) * 256 + g * 8;
#pragma unroll
  for (int half = 0; half < 2; ++half) {
    bf16x8 bf[4][4];
#pragma unroll
    for (int nt = 0; nt < 4; ++nt)
#pragma unroll
      for (int k2 = 0; k2 < 4; ++k2)
        bf[nt][k2] = *(const bf16x8*)(bp + (size_t)nt * 4096 + half * 128 + k2 * 32);
#pragma unroll
    for (int k2 = 0; k2 < 4; ++k2)
#pragma unroll
      for (int nt = 0; nt < 4; ++nt)
        acc[nt] = __builtin_amdgcn_mfma_f32_16x16x32_bf16(af[half * 4 + k2], bf[nt][k2],
                                                          acc[nt], 0, 0, 0);
  }

  const int o0 = m0 + g * 4;
  float b4[4];
#pragma unroll
  for (int r = 0; r < 4; ++r) b4[r] = bias[o0 + r];
#pragma unroll
  for (int nt = 0; nt < 4; ++nt) {
    int n = n0 + nt * 16 + c;
#pragma unroll
    for (int r = 0; r < 4; ++r)
      y[(size_t)(o0 + r) * 4096 + n] = acc[nt][r] + b4[r];
  }
}

extern "C" void kernel_launch(void* const* d_in, const int* in_sizes, int n_in,
                              void* d_out, int out_size, void* d_ws, size_t ws_size,
                              hipStream_t stream) {
  const float* x = (const float*)d_in[0];
  const float* gnw = (const float*)d_in[1];
  const float* gnb = (const float*)d_in[2];
  const float* w_qkv = (const float*)d_in[3];
  const float* w_out = (const float*)d_in[4];
  const float* b_out = (const float*)d_in[5];
  float* ws = (float*)d_ws;

  float2* psum2 = (float2*)ws;                         // 512 float2
  float* bias0 = ws + 1088;                            // 768
  unsigned short* w2b = (unsigned short*)(ws + 2048);  // 768*256 u16
  unsigned short* w_outb = w2b + 196608;               // 256*256 u16
  unsigned short* xTb = w_outb + 65536;                // 4096*256 u16
  unsigned short* qt = xTb + 1048576;                  // 8*4096*32 u16
  unsigned short* ktb = qt + 1048576;
  unsigned short* v16 = ktb + 1048576;                 // tiled V
  unsigned short* outTb = v16 + 1048576;               // 4096*256 u16
  float* y = (float*)d_out;

  hipLaunchKernelGGL(xt_gn_kernel, dim3(64, 4), dim3(256), 0, stream, x, xTb, psum2);
  hipLaunchKernelGGL(fold_all_kernel, dim3(256), dim3(256), 0, stream, w_qkv, gnw, gnb,
                     psum2, w_out, w2b, bias0, w_outb);
  hipLaunchKernelGGL(gemm_qkv_mfma, dim3(64, 12), dim3(256), 0, stream, w2b, xTb, bias0, qt, ktb, v16);
  hipLaunchKernelGGL(attn_mfma_kernel, dim3(256), dim3(512), 0, stream, qt, ktb, v16, outTb);
  hipLaunchKernelGGL(gemm_out_mfma, dim3(64, 4), dim3(256), 0, stream, w_outb, outTb, b_out, y);
}

// Round 17
// 68.818 us; speedup vs baseline: 1.1084x; 1.0604x over previous
//
#include <hip/hip_runtime.h>
#include <hip/hip_bf16.h>
#include <math.h>

// AttentionBlock3D: b=1, C=256, n=4096, 8 heads x 32 dim, GROUPS=8, EPS=1e-5
// FINAL (= r12, best measured: 68.6us, absmax 6.1e-5):
//  KA xt_gn:     x f32 [256][4096] -> xTb bf16 [4096][256] + gn partial sums
//  KB fold_all:  stats + fold groupnorm into QKV weights + w_out cast
//  KC gemm_qkv_mfma: qkv = w2b @ x (bf16 MFMA). Outputs qt[h][pos][32]
//                (Q pre-scaled LOG2E/sqrt(d)), ktb[h][pos][32],
//                v16[h][j/16][32][16]
//  KD attn_mfma: 512 blocks x 512 thr, 64 q/block, 8 waves j-split,
//                2x-unrolled K/V register prefetch, no online max
//                (|s| bounded: exp2 direct on log2-unit scores),
//                truncation P-pack + ones-MFMA denominator over the SAME
//                truncated bits (self-consistent; bias cancels in p/l),
//                chunked per-i-tile LDS merge.
//  KE gemm_out_mfma: y = w_outb @ outTb^T + b_out (bf16 MFMA, f32 out)

typedef __attribute__((ext_vector_type(8))) short bf16x8;
typedef __attribute__((ext_vector_type(4))) short bf16x4;
typedef __attribute__((ext_vector_type(4))) float f32x4;
typedef __attribute__((ext_vector_type(4))) unsigned short u16x4;

__device__ inline unsigned short f2bf(float f) {
  __hip_bfloat16 h = __float2bfloat16(f);
  return *reinterpret_cast<unsigned short*>(&h);
}

// ---------------- KA: transpose + groupnorm partial sums ----------------
__global__ __launch_bounds__(256) void xt_gn_kernel(const float* __restrict__ x,
                                                    unsigned short* __restrict__ xTb,
                                                    float2* __restrict__ psum2) {
  __shared__ float tile[64][65];
  __shared__ float red[4][4];
  int nb = blockIdx.x * 64, cb = blockIdx.y * 64;
  int tn = threadIdx.x & 63, t4 = threadIdx.x >> 6;
  float slo = 0.f, qlo = 0.f, shi = 0.f, qhi = 0.f;
#pragma unroll
  for (int i = 0; i < 16; ++i) {
    int cc = t4 + i * 4;
    float v = x[(size_t)(cb + cc) * 4096 + nb + tn];
    tile[cc][tn] = v;
    if (i < 8) { slo += v; qlo += v * v; } else { shi += v; qhi += v * v; }
  }
#pragma unroll
  for (int off = 32; off > 0; off >>= 1) {
    slo += __shfl_down(slo, off); qlo += __shfl_down(qlo, off);
    shi += __shfl_down(shi, off); qhi += __shfl_down(qhi, off);
  }
  if ((threadIdx.x & 63) == 0) {
    red[t4][0] = slo; red[t4][1] = qlo; red[t4][2] = shi; red[t4][3] = qhi;
  }
  __syncthreads();
  if (threadIdx.x == 0) {
    float a = (red[0][0] + red[1][0]) + (red[2][0] + red[3][0]);
    float b = (red[0][1] + red[1][1]) + (red[2][1] + red[3][1]);
    psum2[(blockIdx.y * 2) * 64 + blockIdx.x] = make_float2(a, b);
  } else if (threadIdx.x == 64) {
    float a = (red[0][2] + red[1][2]) + (red[2][2] + red[3][2]);
    float b = (red[0][3] + red[1][3]) + (red[2][3] + red[3][3]);
    psum2[(blockIdx.y * 2 + 1) * 64 + blockIdx.x] = make_float2(a, b);
  }
#pragma unroll
  for (int i = 0; i < 16; ++i) {
    int nn = t4 + i * 4;
    xTb[(size_t)(nb + nn) * 256 + cb + tn] = f2bf(tile[tn][nn]);
  }
}

// ---------------- KB: stats + fold + w_out cast ----------------
__global__ __launch_bounds__(256) void fold_all_kernel(const float* __restrict__ w_qkv,
                                                       const float* __restrict__ gnw,
                                                       const float* __restrict__ gnb,
                                                       const float2* __restrict__ psum2,
                                                       const float* __restrict__ w_out,
                                                       unsigned short* __restrict__ w2b,
                                                       float* __restrict__ bias0,
                                                       unsigned short* __restrict__ w_outb) {
  int bid = blockIdx.x;
  int t = threadIdx.x;
  if (bid >= 192) {  // w_out -> bf16
    int i = ((bid - 192) * 256 + t) * 4;
    float4 v = *(const float4*)(w_out + i);
    u16x4 o;
    o[0] = f2bf(v.x); o[1] = f2bf(v.y); o[2] = f2bf(v.z); o[3] = f2bf(v.w);
    *(u16x4*)(w_outb + i) = o;
    return;
  }
  __shared__ float sm[8], sr[8];
  __shared__ float s_al[256], s_be[256];
  {
    int g = t >> 5, ii = t & 31;
    float2 p0 = psum2[g * 64 + ii];
    float2 p1 = psum2[g * 64 + 32 + ii];
    float s = p0.x + p1.x, q = p0.y + p1.y;
#pragma unroll
    for (int off = 16; off > 0; off >>= 1) {
      s += __shfl_xor(s, off);
      q += __shfl_xor(q, off);
    }
    if (ii == 0) {
      float mean = s * (1.f / 131072.f);
      float var = q * (1.f / 131072.f) - mean * mean;
      sm[g] = mean;
      sr[g] = rsqrtf(var + 1e-5f);
    }
  }
  __syncthreads();
  {
    int c = t, gg = c >> 5;
    float mean = sm[gg], rstd = sr[gg];
    float al = rstd * gnw[c];
    s_al[c] = al;
    s_be[c] = gnb[c] - mean * al;
  }
  __syncthreads();
  int w = t >> 6, lane = t & 63;
  int row = bid * 4 + w;
  float4 v = *(const float4*)(w_qkv + row * 256 + lane * 4);
  int c0 = lane * 4;
  float part = (v.x * s_be[c0] + v.y * s_be[c0 + 1]) +
               (v.z * s_be[c0 + 2] + v.w * s_be[c0 + 3]);
  u16x4 o;
  o[0] = f2bf(v.x * s_al[c0]);
  o[1] = f2bf(v.y * s_al[c0 + 1]);
  o[2] = f2bf(v.z * s_al[c0 + 2]);
  o[3] = f2bf(v.w * s_al[c0 + 3]);
  *(u16x4*)(w2b + row * 256 + c0) = o;
#pragma unroll
  for (int off = 32; off > 0; off >>= 1) part += __shfl_down(part, off);
  if (lane == 0) bias0[row] = part;
}

// ---------------- KC: qkv GEMM, bf16 MFMA ----------------
__global__ __launch_bounds__(256) void gemm_qkv_mfma(const unsigned short* __restrict__ w2b,
                                                     const unsigned short* __restrict__ xTb,
                                                     const float* __restrict__ bias0,
                                                     unsigned short* __restrict__ qt,
                                                     unsigned short* __restrict__ ktb,
                                                     unsigned short* __restrict__ v16) {
  const int nb = blockIdx.x, mb = blockIdx.y;
  const int t = threadIdx.x;
  const int w = t >> 6, lane = t & 63;
  const int c = lane & 15, g = lane >> 4;
  const int m0 = mb * 64 + w * 16;
  const int n0 = nb * 64;
  const f32x4 zero4 = {0.f, 0.f, 0.f, 0.f};

  const unsigned short* ap = w2b + (size_t)(m0 + c) * 256 + g * 8;
  bf16x8 af[8];
#pragma unroll
  for (int ks = 0; ks < 8; ++ks) af[ks] = *(const bf16x8*)(ap + ks * 32);

  f32x4 acc[4] = {zero4, zero4, zero4, zero4};
  const unsigned short* bp = xTb + (size_t)(n0 + c) * 256 + g * 8;
#pragma unroll
  for (int half = 0; half < 2; ++half) {
    bf16x8 bf[4][4];
#pragma unroll
    for (int nt = 0; nt < 4; ++nt)
#pragma unroll
      for (int k2 = 0; k2 < 4; ++k2)
        bf[nt][k2] = *(const bf16x8*)(bp + (size_t)nt * 4096 + half * 128 + k2 * 32);
#pragma unroll
    for (int k2 = 0; k2 < 4; ++k2)
#pragma unroll
      for (int nt = 0; nt < 4; ++nt)
        acc[nt] = __builtin_amdgcn_mfma_f32_16x16x32_bf16(af[half * 4 + k2], bf[nt][k2],
                                                          acc[nt], 0, 0, 0);
  }

  const int o0 = m0 + g * 4;
  const int t3 = o0 >> 8;
  const int h = (o0 >> 5) & 7;
  const int d0 = o0 & 31;
  float b4[4];
#pragma unroll
  for (int r = 0; r < 4; ++r) b4[r] = bias0[o0 + r];
  // Q pre-scale: 1/sqrt(32) * log2(e) so scores exit QK^T in log2 units
  const float qs = 0.17677669529663687f * 1.4426950408889634f;
#pragma unroll
  for (int nt = 0; nt < 4; ++nt) {
    int n = n0 + nt * 16 + c;
    if (t3 == 0) {
      u16x4 v;
#pragma unroll
      for (int r = 0; r < 4; ++r) v[r] = f2bf((acc[nt][r] + b4[r]) * qs);
      *(u16x4*)(qt + (size_t)(h * 4096 + n) * 32 + d0) = v;
    } else if (t3 == 1) {
      u16x4 v;
#pragma unroll
      for (int r = 0; r < 4; ++r) v[r] = f2bf(acc[nt][r] + b4[r]);
      *(u16x4*)(ktb + (size_t)(h * 4096 + n) * 32 + d0) = v;
    } else {
#pragma unroll
      for (int r = 0; r < 4; ++r)
        v16[(size_t)((h * 256 + (n >> 4)) * 32 + d0 + r) * 16 + (n & 15)] =
            f2bf(acc[nt][r] + b4[r]);
    }
  }
}

// ---------------- KD: MFMA flash attention, no online max ----------------
// One (jt) compute step over a 64j x 64q tile set.
// P pack: truncation (top 16 bits). Denominator: ones-row MFMA over the
// SAME truncated bits (self-consistent; bias cancels in p/l; fp32 accum).
__device__ __forceinline__ void attn_step(const bf16x8* kf, const bf16x4 vf[2][4],
                                          const bf16x8* qf, f32x4 (*oacc)[2],
                                          f32x4* lones) {
  const f32x4 zero4 = {0.f, 0.f, 0.f, 0.f};
  const short one_bf = (short)0x3F80;
  const bf16x4 onesv = {one_bf, one_bf, one_bf, one_bf};
#pragma unroll
  for (int it = 0; it < 4; ++it) {
    f32x4 st[4];
    __builtin_amdgcn_s_setprio(1);
#pragma unroll
    for (int js = 0; js < 4; ++js)
      st[js] = __builtin_amdgcn_mfma_f32_16x16x32_bf16(kf[js], qf[it], zero4, 0, 0, 0);
    __builtin_amdgcn_s_setprio(0);
    bf16x4 pb[4];
#pragma unroll
    for (int js = 0; js < 4; ++js) {
      // scores already in log2 units (Q pre-scaled by LOG2E/sqrt(d))
      unsigned u0 = __float_as_uint(__builtin_amdgcn_exp2f(st[js][0]));
      unsigned u1 = __float_as_uint(__builtin_amdgcn_exp2f(st[js][1]));
      unsigned u2 = __float_as_uint(__builtin_amdgcn_exp2f(st[js][2]));
      unsigned u3 = __float_as_uint(__builtin_amdgcn_exp2f(st[js][3]));
      union { unsigned u[2]; bf16x4 v; } pu;
      pu.u[0] = (u0 >> 16) | (u1 & 0xFFFF0000u);  // elem0=bf16(p0), elem1=bf16(p1)
      pu.u[1] = (u2 >> 16) | (u3 & 0xFFFF0000u);
      pb[js] = pu.v;
    }
    __builtin_amdgcn_s_setprio(1);
#pragma unroll
    for (int js = 0; js < 4; ++js) {
      oacc[it][0] = __builtin_amdgcn_mfma_f32_16x16x16bf16_1k(vf[0][js], pb[js], oacc[it][0], 0, 0, 0);
      oacc[it][1] = __builtin_amdgcn_mfma_f32_16x16x16bf16_1k(vf[1][js], pb[js], oacc[it][1], 0, 0, 0);
      lones[it] = __builtin_amdgcn_mfma_f32_16x16x16bf16_1k(onesv, pb[js], lones[it], 0, 0, 0);
    }
    __builtin_amdgcn_s_setprio(0);
  }
}

// 512 blocks x 512 threads: h = b&7 (XCD affinity), i0 = (b>>3)*64.
// 8 waves split j (512 each). 2x-unrolled jt pipeline, two K+V register sets.
__global__ __launch_bounds__(512, 1) void attn_mfma_kernel(const unsigned short* __restrict__ qt,
                                                           const unsigned short* __restrict__ ktb,
                                                           const unsigned short* __restrict__ v16,
                                                           unsigned short* __restrict__ outTb) {
  const int b = blockIdx.x;
  const int h = b & 7;
  const int i0 = (b >> 3) * 64;
  const int t = threadIdx.x;
  const int w = t >> 6;
  const int lane = t & 63;
  const int c = lane & 15;
  const int g = lane >> 4;
  const f32x4 zero4 = {0.f, 0.f, 0.f, 0.f};

  const unsigned short* qb = qt + (size_t)h * 131072 + (size_t)(i0 + c) * 32 + g * 8;
  bf16x8 qf[4];
#pragma unroll
  for (int it = 0; it < 4; ++it) qf[it] = *(const bf16x8*)(qb + it * 512);

  const unsigned short* kp = ktb + (size_t)h * 131072 + (size_t)(w * 512 + c) * 32 + g * 8;
  const unsigned short* vp = v16 + (size_t)((h * 256 + w * 32) * 32 + c) * 16 + g * 4;

  f32x4 lones[4] = {zero4, zero4, zero4, zero4};
  f32x4 oacc[4][2];
#pragma unroll
  for (int it = 0; it < 4; ++it) {
    oacc[it][0] = zero4;
    oacc[it][1] = zero4;
  }

#define KLOAD(dst, tt)                                         \
  _Pragma("unroll") for (int js = 0; js < 4; ++js)             \
      dst[js] = *(const bf16x8*)(kp + (tt) * 2048 + js * 512);
#define VLOAD(dst, tt)                                                        \
  _Pragma("unroll") for (int dh = 0; dh < 2; ++dh)                            \
      _Pragma("unroll") for (int js = 0; js < 4; ++js)                        \
          dst[dh][js] = *(const bf16x4*)(vp + ((tt) * 4 + js) * 512 + dh * 256);

  bf16x8 kfA[4], kfB[4];
  bf16x4 vfA[2][4], vfB[2][4];
  KLOAD(kfA, 0);
  VLOAD(vfA, 0);

#pragma unroll 1
  for (int jt2 = 0; jt2 < 4; ++jt2) {
    const int base = jt2 * 2;
    KLOAD(kfB, base + 1);
    VLOAD(vfB, base + 1);
    attn_step(kfA, vfA, qf, oacc, lones);
    if (jt2 < 3) {
      KLOAD(kfA, base + 2);
      VLOAD(vfA, base + 2);
    }
    attn_step(kfB, vfB, qf, oacc, lones);
  }
#undef KLOAD
#undef VLOAD

  // ---- merge 8 waves' partials, chunked per i-tile (LDS ~19.5KB) ----
  // ones-MFMA puts the full column sum Sum_j p~[j][c] in every acc element,
  // so lones[it][0] is the per-query denominator directly (no shfl needed).
  __shared__ float lds_o[8][2][4][4][17];  // [w][dh][g][r][c] (one i-tile)
  __shared__ float lds_l[8][4][16];
#pragma unroll
  for (int it = 0; it < 4; ++it) {
    if (g == 0) lds_l[w][it][c] = lones[it][0];
  }
#pragma unroll 1
  for (int itc = 0; itc < 4; ++itc) {
#pragma unroll
    for (int dh = 0; dh < 2; ++dh)
#pragma unroll
      for (int r = 0; r < 4; ++r)
        lds_o[w][dh][g][r][c] = oacc[itc][dh][r];
    __syncthreads();
    if (w < 2) {
      const int dh = w;
      float L = ((lds_l[0][itc][c] + lds_l[1][itc][c]) + (lds_l[2][itc][c] + lds_l[3][itc][c])) +
                ((lds_l[4][itc][c] + lds_l[5][itc][c]) + (lds_l[6][itc][c] + lds_l[7][itc][c]));
      float inv = 1.f / L;
      u16x4 o;
#pragma unroll
      for (int r = 0; r < 4; ++r) {
        float v = ((lds_o[0][dh][g][r][c] + lds_o[1][dh][g][r][c]) +
                   (lds_o[2][dh][g][r][c] + lds_o[3][dh][g][r][c])) +
                  ((lds_o[4][dh][g][r][c] + lds_o[5][dh][g][r][c]) +
                   (lds_o[6][dh][g][r][c] + lds_o[7][dh][g][r][c]));
        o[r] = f2bf(v * inv);
      }
      *(u16x4*)(outTb + (size_t)(i0 + itc * 16 + c) * 256 + h * 32 + dh * 16 + g * 4) = o;
    }
    __syncthreads();
  }
}

// ---------------- KE: y = w_outb @ outTb^T + b_out (bf16 MFMA) ----------------
__global__ __launch_bounds__(256) void gemm_out_mfma(const unsigned short* __restrict__ w_outb,
                                                     const unsigned short* __restrict__ outTb,
                                                     const float* __restrict__ bias,
                                                     float* __restrict__ y) {
  const int nb = blockIdx.x, mb = blockIdx.y;
  const int t = threadIdx.x;
  const int w = t >> 6, lane = t & 63;
  const int c = lane & 15, g = lane >> 4;
  const int m0 = mb * 64 + w * 16;
  const int n0 = nb * 64;
  const f32x4 zero4 = {0.f, 0.f, 0.f, 0.f};

  const unsigned short* ap = w_outb + (size_t)(m0 + c) * 256 + g * 8;
  bf16x8 af[8];
#pragma unroll
  for (int ks = 0; ks < 8; ++ks) af[ks] = *(const bf16x8*)(ap + ks * 32);

  f32x4 acc[4] = {zero4, zero4, zero4, zero4};
  const unsigned short* bp = outTb + (size_t)(n0 + c) * 256 + g * 8;
#pragma unroll
  for (int half = 0; half < 2; ++half) {
    bf16x8 bf[4][4];
#pragma unroll
    for (int nt = 0; nt < 4; ++nt)
#pragma unroll
      for (int k2 = 0; k2 < 4; ++k2)
        bf[nt][k2] = *(const bf16x8*)(bp + (size_t)nt * 4096 + half * 128 + k2 * 32);
#pragma unroll
    for (int k2 = 0; k2 < 4; ++k2)
#pragma unroll
      for (int nt = 0; nt < 4; ++nt)
        acc[nt] = __builtin_amdgcn_mfma_f32_16x16x32_bf16(af[half * 4 + k2], bf[nt][k2],
                                                          acc[nt], 0, 0, 0);
  }

  const int o0 = m0 + g * 4;
  float b4[4];
#pragma unroll
  for (int r = 0; r < 4; ++r) b4[r] = bias[o0 + r];
#pragma unroll
  for (int nt = 0; nt < 4; ++nt) {
    int n = n0 + nt * 16 + c;
#pragma unroll
    for (int r = 0; r < 4; ++r)
      y[(size_t)(o0 + r) * 4096 + n] = acc[nt][r] + b4[r];
  }
}

extern "C" void kernel_launch(void* const* d_in, const int* in_sizes, int n_in,
                              void* d_out, int out_size, void* d_ws, size_t ws_size,
                              hipStream_t stream) {
  const float* x = (const float*)d_in[0];
  const float* gnw = (const float*)d_in[1];
  const float* gnb = (const float*)d_in[2];
  const float* w_qkv = (const float*)d_in[3];
  const float* w_out = (const float*)d_in[4];
  const float* b_out = (const float*)d_in[5];
  float* ws = (float*)d_ws;

  float2* psum2 = (float2*)ws;                         // 512 float2
  float* bias0 = ws + 1088;                            // 768
  unsigned short* w2b = (unsigned short*)(ws + 2048);  // 768*256 u16
  unsigned short* w_outb = w2b + 196608;               // 256*256 u16
  unsigned short* xTb = w_outb + 65536;                // 4096*256 u16
  unsigned short* qt = xTb + 1048576;                  // 8*4096*32 u16
  unsigned short* ktb = qt + 1048576;
  unsigned short* v16 = ktb + 1048576;                 // tiled V
  unsigned short* outTb = v16 + 1048576;               // 4096*256 u16
  float* y = (float*)d_out;

  hipLaunchKernelGGL(xt_gn_kernel, dim3(64, 4), dim3(256), 0, stream, x, xTb, psum2);
  hipLaunchKernelGGL(fold_all_kernel, dim3(256), dim3(256), 0, stream, w_qkv, gnw, gnb,
                     psum2, w_out, w2b, bias0, w_outb);
  hipLaunchKernelGGL(gemm_qkv_mfma, dim3(64, 12), dim3(256), 0, stream, w2b, xTb, bias0, qt, ktb, v16);
  hipLaunchKernelGGL(attn_mfma_kernel, dim3(512), dim3(512), 0, stream, qt, ktb, v16, outTb);
  hipLaunchKernelGGL(gemm_out_mfma, dim3(64, 4), dim3(256), 0, stream, w_outb, outTb, b_out, y);
}